// Round 9
// baseline (343.905 us; speedup 1.0000x reference)
//
#include <hip/hip_runtime.h>
#include <math.h>

#define NQ   8192
#define NK   4096
#define DIM  768
#define LL   8

typedef _Float16 f16;
typedef __attribute__((ext_vector_type(4))) _Float16 f16x4;
typedef __attribute__((ext_vector_type(8))) _Float16 f16x8;
typedef __attribute__((ext_vector_type(4))) float f32x4;
typedef unsigned long long u64;

__device__ inline unsigned ordf(float f) {           // monotonic f32->u32
    unsigned u = __float_as_uint(f);
    return (u & 0x80000000u) ? ~u : (u | 0x80000000u);
}

__device__ __forceinline__ void gload16(const void* g, void* l) {
    __builtin_amdgcn_global_load_lds((const __attribute__((address_space(1))) void*)g,
                                     (__attribute__((address_space(3))) void*)l, 16, 0, 0);
}

// ---------- prep: f16 conversion of x (rows 0..8191) and e_k (rows 8192..12287) ----------
__global__ __launch_bounds__(256) void prep(const float* __restrict__ xq,
                                            const float* __restrict__ ek,
                                            f16* __restrict__ Xh,
                                            f16* __restrict__ Eh,
                                            float* __restrict__ margin,
                                            float* __restrict__ inv_n) {
    const int wid = threadIdx.x >> 6, lane = threadIdx.x & 63;
    const int row = blockIdx.x * 4 + wid;              // 0..12287
    const bool isX = row < NQ;
    const f32x4* src = (const f32x4*)(isX ? xq + (size_t)row * DIM
                                          : ek + (size_t)(row - NQ) * DIM);
    f16x4* dst = (f16x4*)(isX ? Xh + (size_t)row * DIM : Eh + (size_t)(row - NQ) * DIM);
    float s2 = 0.f;
#pragma unroll
    for (int j = 0; j < 3; ++j) {
        const f32x4 v = src[j * 64 + lane];
        s2 = fmaf(v.x, v.x, fmaf(v.y, v.y, fmaf(v.z, v.z, fmaf(v.w, v.w, s2))));
        dst[j * 64 + lane] = (f16x4){(f16)v.x, (f16)v.y, (f16)v.z, (f16)v.w};
    }
#pragma unroll
    for (int off = 32; off; off >>= 1) s2 += __shfl_xor(s2, off);
    if (lane == 0) {
        if (isX) margin[row] = sqrtf(s2) * 1.5e-4f + 2e-3f;   // ~13 sigma of fp16 noise
        else     inv_n[row - NQ] = 1.0f / fmaxf(sqrtf(s2), 1e-12f);
    }
}

// ---------- 256x256 f16 GEMM, double-buffered LDS, counted vmcnt, swizzled LDS ----------
// 8 waves (2M x 4N), wave tile 128x64, BK=64, NT = 768/64 = 12 K-tiles.
// LDS: A,B: 2 bufs x 256 rows x 64 cols f16 = 128 KB total. 1 block/CU.
// Swizzle: 16B slot s of row r holds global cols ((s ^ (r&7))*8..+8)  [involution]
__global__ __launch_bounds__(512, 2) void gemm256p(const f16* __restrict__ Xh,
                                                   const f16* __restrict__ Eh,
                                                   const float* __restrict__ inv_n,
                                                   f16* __restrict__ scor) {
    __shared__ f16 A[2][256 * 64], B[2][256 * 64];
    const int t = threadIdx.x, lane = t & 63, wid = t >> 6;
    const int wm = wid & 1, wn = wid >> 1;
    const int qbase = blockIdx.x * 256, kbase = blockIdx.y * 256;

    f32x4 acc[8][4];
#pragma unroll
    for (int mi = 0; mi < 8; ++mi)
#pragma unroll
        for (int ni = 0; ni < 4; ++ni) acc[mi][ni] = (f32x4){0.f, 0.f, 0.f, 0.f};

    // staging: thread t -> LDS row (t>>3)+p*64, slot (t&7); source slot swizzled
    const int srow = t >> 3, sslot = t & 7;
    const int gslot = sslot ^ (srow & 7);
    const f16* gA = Xh + (size_t)(qbase + srow) * DIM + gslot * 8;
    const f16* gB = Eh + (size_t)(kbase + srow) * DIM + gslot * 8;

#define STAGE(buf, kk)                                                        \
    {                                                                         \
        _Pragma("unroll")                                                     \
        for (int p = 0; p < 4; ++p) {                                         \
            gload16(gA + (size_t)(p * 64) * DIM + (kk), &A[buf][p * 4096 + t * 8]); \
            gload16(gB + (size_t)(p * 64) * DIM + (kk), &B[buf][p * 4096 + t * 8]); \
        }                                                                     \
    }

    // fragment read addresses (swizzled): row r, slot s -> &X[r*64 + (s^(r&7))*8]
    const int rlow = lane & 15, quad = lane >> 4;

#define TILE_COMPUTE(cur)                                                     \
    {                                                                         \
        _Pragma("unroll")                                                     \
        for (int kk2 = 0; kk2 < 2; ++kk2) {                                   \
            f16x8 bh[4];                                                      \
            _Pragma("unroll")                                                 \
            for (int ni = 0; ni < 4; ++ni) {                                  \
                const int r = wn * 64 + ni * 16 + rlow;                       \
                const int s = (kk2 * 4 + quad) ^ (r & 7);                     \
                bh[ni] = *(const f16x8*)&B[cur][r * 64 + s * 8];              \
            }                                                                 \
            _Pragma("unroll")                                                 \
            for (int h = 0; h < 2; ++h) {                                     \
                f16x8 ah[4];                                                  \
                _Pragma("unroll")                                             \
                for (int i = 0; i < 4; ++i) {                                 \
                    const int r = wm * 128 + (h * 4 + i) * 16 + rlow;         \
                    const int s = (kk2 * 4 + quad) ^ (r & 7);                 \
                    ah[i] = *(const f16x8*)&A[cur][r * 64 + s * 8];           \
                }                                                             \
                __builtin_amdgcn_s_setprio(1);                                \
                _Pragma("unroll")                                             \
                for (int i = 0; i < 4; ++i)                                   \
                    _Pragma("unroll")                                         \
                    for (int ni = 0; ni < 4; ++ni)                            \
                        acc[h * 4 + i][ni] = __builtin_amdgcn_mfma_f32_16x16x32_f16( \
                            ah[i], bh[ni], acc[h * 4 + i][ni], 0, 0, 0);      \
                __builtin_amdgcn_s_setprio(0);                                \
            }                                                                 \
        }                                                                     \
    }

    // prologue: stage tile 0
    STAGE(0, 0);

#pragma unroll 1
    for (int tt = 0; tt < 11; ++tt) {
        const int cur = tt & 1;
        STAGE(cur ^ 1, (tt + 1) * 64);                 // prefetch next tile
        asm volatile("s_waitcnt vmcnt(8)" ::: "memory"); // cur landed; next 8 in flight
        __builtin_amdgcn_sched_barrier(0);
        __builtin_amdgcn_s_barrier();
        __builtin_amdgcn_sched_barrier(0);
        if (cur) TILE_COMPUTE(1) else TILE_COMPUTE(0);
        __builtin_amdgcn_sched_barrier(0);
        __builtin_amdgcn_s_barrier();                  // cur reads done before t+2 stages it
        __builtin_amdgcn_sched_barrier(0);
    }
    // final tile (11): no prefetch
    asm volatile("s_waitcnt vmcnt(0)" ::: "memory");
    __builtin_amdgcn_sched_barrier(0);
    __builtin_amdgcn_s_barrier();
    __builtin_amdgcn_sched_barrier(0);
    TILE_COMPUTE(1);

    // epilogue: C/D layout col=lane&15, row=(lane>>4)*4+reg (verified r2-r8)
    const int rg = lane >> 4, cid = lane & 15;
    float invv[4];
    int key[4];
#pragma unroll
    for (int ni = 0; ni < 4; ++ni) {
        key[ni] = kbase + wn * 64 + ni * 16 + cid;
        invv[ni] = inv_n[key[ni]];
    }
#pragma unroll
    for (int mi = 0; mi < 8; ++mi)
#pragma unroll
        for (int rj = 0; rj < 4; ++rj) {
            const int row = qbase + wm * 128 + mi * 16 + rg * 4 + rj;
#pragma unroll
            for (int ni = 0; ni < 4; ++ni)
                scor[(size_t)row * NK + key[ni]] = (f16)(acc[mi][ni][rj] * invv[ni]);
        }
#undef STAGE
#undef TILE_COMPUTE
}

// ---------- scan: row max over f16 scores, margin test, wave-coop f32 rescore ----------
__global__ __launch_bounds__(256) void scan_rescore(const f16* __restrict__ scor,
                                                    const float* __restrict__ margin,
                                                    const float* __restrict__ inv_n,
                                                    const float* __restrict__ xq,
                                                    const float* __restrict__ ek,
                                                    int* __restrict__ bestk) {
    const int r = blockIdx.x, t = threadIdx.x, lane = t & 63, wid = t >> 6;
    __shared__ float wmaxs[4];
    __shared__ u64 wbest[4];
    __shared__ int cnt;
    __shared__ int list[256];

    if (t == 0) cnt = 0;

    const f16* srow = scor + (size_t)r * NK + t * 16;
    const f16x8 s0 = *(const f16x8*)srow;
    const f16x8 s1 = *(const f16x8*)(srow + 8);
    float sc[16];
    float m = -INFINITY;
#pragma unroll
    for (int j = 0; j < 8; ++j) { sc[j] = (float)s0[j]; sc[j + 8] = (float)s1[j]; }
#pragma unroll
    for (int j = 0; j < 16; ++j) m = fmaxf(m, sc[j]);
#pragma unroll
    for (int off = 32; off; off >>= 1) m = fmaxf(m, __shfl_xor(m, off));
    if (lane == 0) wmaxs[wid] = m;
    __syncthreads();
    m = fmaxf(fmaxf(wmaxs[0], wmaxs[1]), fmaxf(wmaxs[2], wmaxs[3]));
    const float thr = m - margin[r];

#pragma unroll
    for (int j = 0; j < 16; ++j) {
        if (sc[j] >= thr) {
            const int idx = atomicAdd(&cnt, 1);
            if (idx < 256) list[idx] = t * 16 + j;
        }
    }
    __syncthreads();
    const int n = cnt < 256 ? cnt : 256;

    const f32x4* xr = (const f32x4*)(xq + (size_t)r * DIM);
    const f32x4 xa = xr[lane * 3], xb = xr[lane * 3 + 1], xc = xr[lane * 3 + 2];

    u64 best = 0;
    for (int e = wid; e < n; e += 4) {
        const int k = list[e];
        const f32x4* er = (const f32x4*)(ek + (size_t)k * DIM);
        const f32x4 ea = er[lane * 3], eb = er[lane * 3 + 1], ec = er[lane * 3 + 2];
        float s = xa.x * ea.x;
        s = fmaf(xa.y, ea.y, s); s = fmaf(xa.z, ea.z, s); s = fmaf(xa.w, ea.w, s);
        s = fmaf(xb.x, eb.x, s); s = fmaf(xb.y, eb.y, s); s = fmaf(xb.z, eb.z, s);
        s = fmaf(xb.w, eb.w, s); s = fmaf(xc.x, ec.x, s); s = fmaf(xc.y, ec.y, s);
        s = fmaf(xc.z, ec.z, s); s = fmaf(xc.w, ec.w, s);
#pragma unroll
        for (int off = 32; off; off >>= 1) s += __shfl_xor(s, off);
        const float v = s * inv_n[k];
        const u64 p64 = ((u64)ordf(v) << 32) | (unsigned)(NK - 1 - k);
        best = best > p64 ? best : p64;
    }
    if (lane == 0) wbest[wid] = best;
    __syncthreads();
    if (t == 0) {
        u64 b0 = wbest[0];
        b0 = b0 > wbest[1] ? b0 : wbest[1];
        b0 = b0 > wbest[2] ? b0 : wbest[2];
        b0 = b0 > wbest[3] ? b0 : wbest[3];
        bestk[r] = NK - 1 - (int)(unsigned)(b0 & 0xffffffffu);
    }
}

// ---------- flat gather with nontemporal output stores ----------
__global__ __launch_bounds__(256) void gather_flat(const int* __restrict__ bestk,
                                                   const float* __restrict__ e_p,
                                                   const float* __restrict__ x_block,
                                                   f32x4* __restrict__ o) {
    const int EK4 = NQ * 4 * (DIM / 4);          // 6,291,456
    const int XB4 = 2 * EK4;                     // 12,582,912
    const int TOT = XB4 + NQ * (DIM / 4);        // 14,155,776
    const int stride = gridDim.x * 256;
    const f32x4* ep4 = (const f32x4*)e_p;
    const f32x4* xb4 = (const f32x4*)x_block;
#pragma unroll 1
    for (int f = blockIdx.x * 256 + threadIdx.x; f < TOT; f += stride) {
        f32x4 v;
        if (f < XB4) {
            const int g = (f >= EK4) ? f - EK4 : f;
            const int b = g / (4 * DIM / 4);
            const int k = bestk[b];
            const int off = (f >= EK4) ? 4 * (DIM / 4) : 0;
            v = ep4[(size_t)k * (LL * DIM / 4) + off + (g - b * 768)];
        } else {
            v = __builtin_nontemporal_load(&xb4[f - XB4]);
        }
        __builtin_nontemporal_store(v, &o[f]);
    }
}

// ---------- launch ----------
extern "C" void kernel_launch(void* const* d_in, const int* in_sizes, int n_in,
                              void* d_out, int out_size, void* d_ws, size_t ws_size,
                              hipStream_t stream) {
    const float* x_querry = (const float*)d_in[0];
    const float* x_block  = (const float*)d_in[1];
    const float* e_k      = (const float*)d_in[2];
    const float* e_p      = (const float*)d_in[3];

    // scratch carved from d_out (226.5 MB), fully consumed before gather overwrites it
    char* base = (char*)d_out;
    f16*   Xh   = (f16*)(base);                   // 12,582,912 B
    f16*   Eh   = (f16*)(base + 12582912);        //  6,291,456 B
    float* invn = (float*)(base + 18874368);      //     16,384 B
    float* marg = (float*)(base + 18890752);      //     32,768 B
    f16*   scor = (f16*)(base + 18923520);        // 67,108,864 B -> ends 86,032,384
    int*   bestk = (int*)d_ws;                    // 32 KB (survives into gather)

    prep<<<(NQ + NK) / 4, 256, 0, stream>>>(x_querry, e_k, Xh, Eh, marg, invn);
    gemm256p<<<dim3(NQ / 256, NK / 256), 512, 0, stream>>>(Xh, Eh, invn, scor);
    scan_rescore<<<NQ, 256, 0, stream>>>(scor, marg, invn, x_querry, e_k, bestk);
    gather_flat<<<2048, 256, 0, stream>>>(bestk, e_p, x_block, (f32x4*)d_out);
}

// Round 10
// 251.035 us; speedup vs baseline: 1.3699x; 1.3699x over previous
//
#include <hip/hip_runtime.h>
#include <math.h>

#define NQ   8192
#define NK   4096
#define DIM  768
#define LL   8
#define CCAP 128

typedef _Float16 f16;
typedef __attribute__((ext_vector_type(4))) _Float16 f16x4;
typedef __attribute__((ext_vector_type(8))) _Float16 f16x8;
typedef __attribute__((ext_vector_type(4))) float f32x4;
typedef unsigned long long u64;

__device__ inline unsigned ordf(float f) {           // monotonic f32->u32
    unsigned u = __float_as_uint(f);
    return (u & 0x80000000u) ? ~u : (u | 0x80000000u);
}
__device__ inline float iord(unsigned u) {           // inverse of ordf
    unsigned b = (u & 0x80000000u) ? (u & 0x7fffffffu) : ~u;
    return __uint_as_float(b);
}

__device__ __forceinline__ void gload16(const void* g, void* l) {
    __builtin_amdgcn_global_load_lds((const __attribute__((address_space(1))) void*)g,
                                     (__attribute__((address_space(3))) void*)l, 16, 0, 0);
}

// ---------- prep: f16 conversion of x (rows 0..8191) and e_k (rows 8192..12287) ----------
__global__ __launch_bounds__(256) void prep(const float* __restrict__ xq,
                                            const float* __restrict__ ek,
                                            f16* __restrict__ Xh,
                                            f16* __restrict__ Eh,
                                            float* __restrict__ margin,
                                            float* __restrict__ inv_n) {
    const int wid = threadIdx.x >> 6, lane = threadIdx.x & 63;
    const int row = blockIdx.x * 4 + wid;              // 0..12287
    const bool isX = row < NQ;
    const f32x4* src = (const f32x4*)(isX ? xq + (size_t)row * DIM
                                          : ek + (size_t)(row - NQ) * DIM);
    f16x4* dst = (f16x4*)(isX ? Xh + (size_t)row * DIM : Eh + (size_t)(row - NQ) * DIM);
    float s2 = 0.f;
#pragma unroll
    for (int j = 0; j < 3; ++j) {
        const f32x4 v = src[j * 64 + lane];
        s2 = fmaf(v.x, v.x, fmaf(v.y, v.y, fmaf(v.z, v.z, fmaf(v.w, v.w, s2))));
        dst[j * 64 + lane] = (f16x4){(f16)v.x, (f16)v.y, (f16)v.z, (f16)v.w};
    }
#pragma unroll
    for (int off = 32; off; off >>= 1) s2 += __shfl_xor(s2, off);
    if (lane == 0) {
        if (isX) margin[row] = sqrtf(s2) * 1.5e-4f + 2e-3f;   // ~13 sigma of fp16 noise
        else     inv_n[row - NQ] = 1.0f / fmaxf(sqrtf(s2), 1e-12f);
    }
}

// ---------- m97-structure fp16 MFMA GEMM + fused candidate emit ----------
// 128x128 tile, BK=64, 4 waves (2x2 of 64x64), global_load_lds w=16, linear LDS.
// (Round-9 lesson: no hand-pinned scheduling — compiler owns the schedule.)
__global__ __launch_bounds__(256) void gemm97f(const f16* __restrict__ Xh,
                                               const f16* __restrict__ Eh,
                                               const float* __restrict__ inv_n,
                                               const float* __restrict__ marg,
                                               int* __restrict__ cnt,
                                               u64* __restrict__ cand) {
    __shared__ f16 A[128 * 64], B[128 * 64];
    __shared__ float rmax[2][128];
    const int t = threadIdx.x, lane = t & 63, wid = t >> 6;
    const int wm = wid & 1, wn = wid >> 1;
    const int qbase = blockIdx.x * 128, kbase = blockIdx.y * 128;

    f32x4 acc[4][4];
#pragma unroll
    for (int mi = 0; mi < 4; ++mi)
#pragma unroll
        for (int ni = 0; ni < 4; ++ni) acc[mi][ni] = (f32x4){0.f, 0.f, 0.f, 0.f};

    const int srow = wid * 8 + (lane >> 3);
    const int scol = (lane & 7) * 8;
    const f16* gA = Xh + (size_t)(qbase + srow) * DIM + scol;
    const f16* gB = Eh + (size_t)(kbase + srow) * DIM + scol;
    f16* lA = &A[wid * 512 + lane * 8];
    f16* lB = &B[wid * 512 + lane * 8];

    for (int kk = 0; kk < DIM; kk += 64) {
        __syncthreads();
#pragma unroll
        for (int p = 0; p < 4; ++p) {
            gload16(gA + (size_t)(p * 32) * DIM + kk, lA + p * 2048);
            gload16(gB + (size_t)(p * 32) * DIM + kk, lB + p * 2048);
        }
        __syncthreads();

#pragma unroll
        for (int kk2 = 0; kk2 < 2; ++kk2) {
            const int ko = kk2 * 32 + (lane >> 4) * 8;
            f16x8 ah[4], bh[4];
#pragma unroll
            for (int mi = 0; mi < 4; ++mi)
                ah[mi] = *(const f16x8*)&A[(wm * 64 + mi * 16 + (lane & 15)) * 64 + ko];
#pragma unroll
            for (int ni = 0; ni < 4; ++ni)
                bh[ni] = *(const f16x8*)&B[(wn * 64 + ni * 16 + (lane & 15)) * 64 + ko];
#pragma unroll
            for (int mi = 0; mi < 4; ++mi)
#pragma unroll
                for (int ni = 0; ni < 4; ++ni)
                    acc[mi][ni] = __builtin_amdgcn_mfma_f32_16x16x32_f16(ah[mi], bh[ni], acc[mi][ni], 0, 0, 0);
        }
    }

    // ---- fused epilogue (functionally verified round 8) ----
    // C/D layout: col = lane&15, row = (lane>>4)*4 + reg
    const int rg = lane >> 4, cid = lane & 15;
    float invv[4];
    int key[4];
#pragma unroll
    for (int ni = 0; ni < 4; ++ni) {
        key[ni] = kbase + wn * 64 + ni * 16 + cid;
        invv[ni] = inv_n[key[ni]];
    }

    // pass 1: per-row max over this block's 128 cols
#pragma unroll
    for (int mi = 0; mi < 4; ++mi)
#pragma unroll
        for (int rj = 0; rj < 4; ++rj) {
            float lm = acc[mi][0][rj] * invv[0];
            lm = fmaxf(lm, acc[mi][1][rj] * invv[1]);
            lm = fmaxf(lm, acc[mi][2][rj] * invv[2]);
            lm = fmaxf(lm, acc[mi][3][rj] * invv[3]);
#pragma unroll
            for (int off = 1; off < 16; off <<= 1) lm = fmaxf(lm, __shfl_xor(lm, off));
            if (cid == 0) rmax[wn][wm * 64 + mi * 16 + rg * 4 + rj] = lm;
        }
    __syncthreads();

    // pass 2: block-margin threshold + emit (superset of global-margin set)
#pragma unroll
    for (int mi = 0; mi < 4; ++mi)
#pragma unroll
        for (int rj = 0; rj < 4; ++rj) {
            const int rl = wm * 64 + mi * 16 + rg * 4 + rj;
            const float bm = fmaxf(rmax[0][rl], rmax[1][rl]);
            const int row = qbase + rl;
            const float thr = bm - marg[row];
#pragma unroll
            for (int ni = 0; ni < 4; ++ni) {
                const float v = acc[mi][ni][rj] * invv[ni];
                if (v >= thr) {
                    const int idx = atomicAdd(&cnt[row], 1);
                    if (idx < CCAP)
                        cand[(size_t)row * CCAP + idx] =
                            ((u64)ordf(v) << 32) | (unsigned)key[ni];
                }
            }
        }
}

// ---------- resolve: candidate max -> margin -> exact f32 rescore -> argmax ----------
__global__ __launch_bounds__(256) void resolve(const int* __restrict__ cnt,
                                               const u64* __restrict__ cand,
                                               const float* __restrict__ marg,
                                               const float* __restrict__ inv_n,
                                               const float* __restrict__ xq,
                                               const float* __restrict__ ek,
                                               int* __restrict__ bestk) {
    const int wid = threadIdx.x >> 6, lane = threadIdx.x & 63;
    const int r = blockIdx.x * 4 + wid;               // one wave per query row
    int n = cnt[r];
    n = n < CCAP ? n : CCAP;
    const u64* cr = cand + (size_t)r * CCAP;

    u64 cm = 0;
    for (int e = lane; e < n; e += 64) { const u64 c = cr[e]; cm = cm > c ? cm : c; }
#pragma unroll
    for (int off = 32; off; off >>= 1) {
        const u64 o = __shfl_xor(cm, off);
        cm = cm > o ? cm : o;
    }
    const float thr = iord((unsigned)(cm >> 32)) - marg[r];

    const f32x4* xr = (const f32x4*)(xq + (size_t)r * DIM);
    const f32x4 xa = xr[lane * 3], xb = xr[lane * 3 + 1], xc = xr[lane * 3 + 2];

    u64 best = 0;
    for (int e = 0; e < n; ++e) {
        const u64 c = cr[e];
        if (iord((unsigned)(c >> 32)) < thr) continue;
        const int k = (int)(unsigned)(c & 0xffffffffu);
        const f32x4* er = (const f32x4*)(ek + (size_t)k * DIM);
        const f32x4 ea = er[lane * 3], eb = er[lane * 3 + 1], ec = er[lane * 3 + 2];
        float s = xa.x * ea.x;
        s = fmaf(xa.y, ea.y, s); s = fmaf(xa.z, ea.z, s); s = fmaf(xa.w, ea.w, s);
        s = fmaf(xb.x, eb.x, s); s = fmaf(xb.y, eb.y, s); s = fmaf(xb.z, eb.z, s);
        s = fmaf(xb.w, eb.w, s); s = fmaf(xc.x, ec.x, s); s = fmaf(xc.y, ec.y, s);
        s = fmaf(xc.z, ec.z, s); s = fmaf(xc.w, ec.w, s);
#pragma unroll
        for (int off = 32; off; off >>= 1) s += __shfl_xor(s, off);
        const float ve = s * inv_n[k];
        const u64 p64 = ((u64)ordf(ve) << 32) | (unsigned)(NK - 1 - k);
        best = best > p64 ? best : p64;
    }
    if (lane == 0) bestk[r] = NK - 1 - (int)(unsigned)(best & 0xffffffffu);
}

// ---------- flat gather with nontemporal output stores ----------
__global__ __launch_bounds__(256) void gather_flat(const int* __restrict__ bestk,
                                                   const float* __restrict__ e_p,
                                                   const float* __restrict__ x_block,
                                                   f32x4* __restrict__ o) {
    const int EK4 = NQ * 4 * (DIM / 4);          // 6,291,456
    const int XB4 = 2 * EK4;                     // 12,582,912
    const int TOT = XB4 + NQ * (DIM / 4);        // 14,155,776
    const int stride = gridDim.x * 256;
    const f32x4* ep4 = (const f32x4*)e_p;
    const f32x4* xb4 = (const f32x4*)x_block;
#pragma unroll 1
    for (int f = blockIdx.x * 256 + threadIdx.x; f < TOT; f += stride) {
        f32x4 v;
        if (f < XB4) {
            const int g = (f >= EK4) ? f - EK4 : f;
            const int b = g / (4 * DIM / 4);
            const int k = bestk[b];
            const int off = (f >= EK4) ? 4 * (DIM / 4) : 0;
            v = ep4[(size_t)k * (LL * DIM / 4) + off + (g - b * 768)];
        } else {
            v = __builtin_nontemporal_load(&xb4[f - XB4]);
        }
        __builtin_nontemporal_store(v, &o[f]);
    }
}

// ---------- launch ----------
extern "C" void kernel_launch(void* const* d_in, const int* in_sizes, int n_in,
                              void* d_out, int out_size, void* d_ws, size_t ws_size,
                              hipStream_t stream) {
    const float* x_querry = (const float*)d_in[0];
    const float* x_block  = (const float*)d_in[1];
    const float* e_k      = (const float*)d_in[2];
    const float* e_p      = (const float*)d_in[3];

    // scratch carved from d_out (226.5 MB), fully consumed before gather overwrites it
    char* base = (char*)d_out;
    f16*   Xh   = (f16*)(base);                   // 12,582,912 B
    f16*   Eh   = (f16*)(base + 12582912);        //  6,291,456 B
    float* invn = (float*)(base + 18874368);      //     16,384 B
    float* marg = (float*)(base + 18890752);      //     32,768 B
    int*   cnt  = (int*)(base + 18923520);        //     32,768 B
    u64*   cand = (u64*)(base + 18956288);        //  8,388,608 B -> ends 27,344,896
    int*   bestk = (int*)d_ws;                    // 32 KB (survives into gather)

    hipMemsetAsync(cnt, 0, NQ * sizeof(int), stream);
    prep<<<(NQ + NK) / 4, 256, 0, stream>>>(x_querry, e_k, Xh, Eh, marg, invn);
    gemm97f<<<dim3(NQ / 128, NK / 128), 256, 0, stream>>>(Xh, Eh, invn, marg, cnt, cand);
    resolve<<<NQ / 4, 256, 0, stream>>>(cnt, cand, marg, invn, x_querry, e_k, bestk);
    gather_flat<<<2048, 256, 0, stream>>>(bestk, e_p, x_block, (f32x4*)d_out);
}

// Round 11
// 151.646 us; speedup vs baseline: 2.2678x; 1.6554x over previous
//
#include <hip/hip_runtime.h>
#include <math.h>

#define NQ   8192
#define NK   4096
#define DIM  768
#define LL   8

typedef _Float16 f16;
typedef __attribute__((ext_vector_type(4))) _Float16 f16x4;
typedef __attribute__((ext_vector_type(8))) _Float16 f16x8;
typedef __attribute__((ext_vector_type(4))) float f32x4;
typedef unsigned long long u64;

__device__ inline unsigned ordf(float f) {           // monotonic f32->u32
    unsigned u = __float_as_uint(f);
    return (u & 0x80000000u) ? ~u : (u | 0x80000000u);
}

__device__ __forceinline__ void gload16(const void* g, void* l) {
    __builtin_amdgcn_global_load_lds((const __attribute__((address_space(1))) void*)g,
                                     (__attribute__((address_space(3))) void*)l, 16, 0, 0);
}

// ---------- prep: f16 conversion of x (rows 0..8191) and e_k (rows 8192..12287) ----------
__global__ __launch_bounds__(256) void prep(const float* __restrict__ xq,
                                            const float* __restrict__ ek,
                                            f16* __restrict__ Xh,
                                            f16* __restrict__ Eh,
                                            float* __restrict__ margin,
                                            float* __restrict__ inv_n) {
    const int wid = threadIdx.x >> 6, lane = threadIdx.x & 63;
    const int row = blockIdx.x * 4 + wid;              // 0..12287
    const bool isX = row < NQ;
    const f32x4* src = (const f32x4*)(isX ? xq + (size_t)row * DIM
                                          : ek + (size_t)(row - NQ) * DIM);
    f16x4* dst = (f16x4*)(isX ? Xh + (size_t)row * DIM : Eh + (size_t)(row - NQ) * DIM);
    float s2 = 0.f;
#pragma unroll
    for (int j = 0; j < 3; ++j) {
        const f32x4 v = src[j * 64 + lane];
        s2 = fmaf(v.x, v.x, fmaf(v.y, v.y, fmaf(v.z, v.z, fmaf(v.w, v.w, s2))));
        dst[j * 64 + lane] = (f16x4){(f16)v.x, (f16)v.y, (f16)v.z, (f16)v.w};
    }
#pragma unroll
    for (int off = 32; off; off >>= 1) s2 += __shfl_xor(s2, off);
    if (lane == 0) {
        if (isX) margin[row] = sqrtf(s2) * 1.5e-4f + 2e-3f;   // ~13 sigma of fp16 noise
        else     inv_n[row - NQ] = 1.0f / fmaxf(sqrtf(s2), 1e-12f);
    }
}

// ---------- 256x256 8-phase pipelined f16 GEMM (T2+T3/T4+T5, no fusion) ----------
// 8 waves (2M x 4N), wave tile 128x64, BK=64, 12 K-tiles, dbuf LDS 128 KB.
// Per K-tile: 4 phases {ds_read A-pair (+B in p0) | issue 2 prefetch gloads |
// s_barrier | setprio MFMA x16 | s_barrier}; tile-boundary __syncthreads is the
// only memory-dependency wait (prefetch issued 4 phases early -> drain cheap).
// LDS swizzle (rule 21, r9-verified mechanics): linear dest, source slot ^= row&7,
// same XOR on ds_read -> 2-way max bank aliasing (free).
__global__ __launch_bounds__(512, 2) void gemm8p(const f16* __restrict__ Xh,
                                                 const f16* __restrict__ Eh,
                                                 const float* __restrict__ inv_n,
                                                 f16* __restrict__ scor) {
    __shared__ f16 Al[2][256 * 64], Bl[2][256 * 64];
    const int t = threadIdx.x, lane = t & 63, wid = t >> 6;
    const int wm = wid & 1, wn = wid >> 1;           // 2M x 4N waves
    const int qbase = blockIdx.x * 256, kbase = blockIdx.y * 256;

    f32x4 acc[8][4];
#pragma unroll
    for (int mi = 0; mi < 8; ++mi)
#pragma unroll
        for (int ni = 0; ni < 4; ++ni) acc[mi][ni] = (f32x4){0.f, 0.f, 0.f, 0.f};

    // staging: thread t -> rows (p*64 + t/8), LDS linear slot t&7; source slot swizzled
    const int srow = t >> 3;                          // 0..63
    const int gslot = (t & 7) ^ (srow & 7);
    const f16* gA = Xh + (size_t)(qbase + srow) * DIM + gslot * 8;
    const f16* gB = Eh + (size_t)(kbase + srow) * DIM + gslot * 8;

    // prologue: stage tile 0
#pragma unroll
    for (int p = 0; p < 4; ++p) {
        gload16(gA + (size_t)(p * 64) * DIM, &Al[0][p * 4096 + t * 8]);
        gload16(gB + (size_t)(p * 64) * DIM, &Bl[0][p * 4096 + t * 8]);
    }
    __syncthreads();

    const int rlow = lane & 15, quad = lane >> 4;

#pragma unroll 1
    for (int tt = 0; tt < 12; ++tt) {
        const int cur = tt & 1;
        const f16* Ab = Al[cur];
        const f16* Bb = Bl[cur];
        f16* An = Al[cur ^ 1];
        f16* Bn = Bl[cur ^ 1];
        const bool pf = (tt + 1) < 12;
        const size_t knext = (size_t)(tt + 1) * 64;

        f16x8 bh[4][2];
#pragma unroll
        for (int p = 0; p < 4; ++p) {
            if (p == 0) {
#pragma unroll
                for (int ni = 0; ni < 4; ++ni)
#pragma unroll
                    for (int k2 = 0; k2 < 2; ++k2) {
                        const int r = wn * 64 + ni * 16 + rlow;
                        const int s = (k2 * 4 + quad) ^ (r & 7);
                        bh[ni][k2] = *(const f16x8*)&Bb[r * 64 + s * 8];
                    }
            }
            f16x8 ah[2][2];
#pragma unroll
            for (int q = 0; q < 2; ++q)
#pragma unroll
                for (int k2 = 0; k2 < 2; ++k2) {
                    const int r = wm * 128 + (p * 2 + q) * 16 + rlow;
                    const int s = (k2 * 4 + quad) ^ (r & 7);
                    ah[q][k2] = *(const f16x8*)&Ab[r * 64 + s * 8];
                }
            if (pf) {
                gload16(gA + (size_t)(p * 64) * DIM + knext, &An[p * 4096 + t * 8]);
                gload16(gB + (size_t)(p * 64) * DIM + knext, &Bn[p * 4096 + t * 8]);
            }
            __builtin_amdgcn_s_barrier();             // rhythmic only (no memory dep)
            __builtin_amdgcn_s_setprio(1);
#pragma unroll
            for (int q = 0; q < 2; ++q)
#pragma unroll
                for (int k2 = 0; k2 < 2; ++k2)
#pragma unroll
                    for (int ni = 0; ni < 4; ++ni)
                        acc[p * 2 + q][ni] = __builtin_amdgcn_mfma_f32_16x16x32_f16(
                            ah[q][k2], bh[ni][k2], acc[p * 2 + q][ni], 0, 0, 0);
            __builtin_amdgcn_s_setprio(0);
            if (p < 3) __builtin_amdgcn_s_barrier();  // rhythmic
        }
        __syncthreads();   // real dep: prefetched tile fully landed; buffers swap
    }

    // epilogue (r7-verified C/D mapping): col=lane&15, row=(lane>>4)*4+reg
    const int rg = lane >> 4, cid = lane & 15;
    float invv[4];
    int key[4];
#pragma unroll
    for (int ni = 0; ni < 4; ++ni) {
        key[ni] = kbase + wn * 64 + ni * 16 + cid;
        invv[ni] = inv_n[key[ni]];
    }
#pragma unroll
    for (int mi = 0; mi < 8; ++mi)
#pragma unroll
        for (int rj = 0; rj < 4; ++rj) {
            const int row = qbase + wm * 128 + mi * 16 + rg * 4 + rj;
#pragma unroll
            for (int ni = 0; ni < 4; ++ni)
                scor[(size_t)row * NK + key[ni]] = (f16)(acc[mi][ni][rj] * invv[ni]);
        }
}

// ---------- scan: row max over f16 scores, margin test, wave-coop f32 rescore ----------
__global__ __launch_bounds__(256) void scan_rescore(const f16* __restrict__ scor,
                                                    const float* __restrict__ margin,
                                                    const float* __restrict__ inv_n,
                                                    const float* __restrict__ xq,
                                                    const float* __restrict__ ek,
                                                    int* __restrict__ bestk) {
    const int r = blockIdx.x, t = threadIdx.x, lane = t & 63, wid = t >> 6;
    __shared__ float wmaxs[4];
    __shared__ u64 wbest[4];
    __shared__ int cnt;
    __shared__ int list[256];

    if (t == 0) cnt = 0;

    const f16* srow = scor + (size_t)r * NK + t * 16;
    const f16x8 s0 = *(const f16x8*)srow;
    const f16x8 s1 = *(const f16x8*)(srow + 8);
    float sc[16];
    float m = -INFINITY;
#pragma unroll
    for (int j = 0; j < 8; ++j) { sc[j] = (float)s0[j]; sc[j + 8] = (float)s1[j]; }
#pragma unroll
    for (int j = 0; j < 16; ++j) m = fmaxf(m, sc[j]);
#pragma unroll
    for (int off = 32; off; off >>= 1) m = fmaxf(m, __shfl_xor(m, off));
    if (lane == 0) wmaxs[wid] = m;
    __syncthreads();
    m = fmaxf(fmaxf(wmaxs[0], wmaxs[1]), fmaxf(wmaxs[2], wmaxs[3]));
    const float thr = m - margin[r];

#pragma unroll
    for (int j = 0; j < 16; ++j) {
        if (sc[j] >= thr) {
            const int idx = atomicAdd(&cnt, 1);
            if (idx < 256) list[idx] = t * 16 + j;
        }
    }
    __syncthreads();
    const int n = cnt < 256 ? cnt : 256;

    const f32x4* xr = (const f32x4*)(xq + (size_t)r * DIM);
    const f32x4 xa = xr[lane * 3], xb = xr[lane * 3 + 1], xc = xr[lane * 3 + 2];

    u64 best = 0;
    for (int e = wid; e < n; e += 4) {
        const int k = list[e];
        const f32x4* er = (const f32x4*)(ek + (size_t)k * DIM);
        const f32x4 ea = er[lane * 3], eb = er[lane * 3 + 1], ec = er[lane * 3 + 2];
        float s = xa.x * ea.x;
        s = fmaf(xa.y, ea.y, s); s = fmaf(xa.z, ea.z, s); s = fmaf(xa.w, ea.w, s);
        s = fmaf(xb.x, eb.x, s); s = fmaf(xb.y, eb.y, s); s = fmaf(xb.z, eb.z, s);
        s = fmaf(xb.w, eb.w, s); s = fmaf(xc.x, ec.x, s); s = fmaf(xc.y, ec.y, s);
        s = fmaf(xc.z, ec.z, s); s = fmaf(xc.w, ec.w, s);
#pragma unroll
        for (int off = 32; off; off >>= 1) s += __shfl_xor(s, off);
        const float v = s * inv_n[k];
        const u64 p64 = ((u64)ordf(v) << 32) | (unsigned)(NK - 1 - k);
        best = best > p64 ? best : p64;
    }
    if (lane == 0) wbest[wid] = best;
    __syncthreads();
    if (t == 0) {
        u64 b0 = wbest[0];
        b0 = b0 > wbest[1] ? b0 : wbest[1];
        b0 = b0 > wbest[2] ? b0 : wbest[2];
        b0 = b0 > wbest[3] ? b0 : wbest[3];
        bestk[r] = NK - 1 - (int)(unsigned)(b0 & 0xffffffffu);
    }
}

// ---------- flat gather with nontemporal output stores ----------
__global__ __launch_bounds__(256) void gather_flat(const int* __restrict__ bestk,
                                                   const float* __restrict__ e_p,
                                                   const float* __restrict__ x_block,
                                                   f32x4* __restrict__ o) {
    const int EK4 = NQ * 4 * (DIM / 4);          // 6,291,456
    const int XB4 = 2 * EK4;                     // 12,582,912
    const int TOT = XB4 + NQ * (DIM / 4);        // 14,155,776
    const int stride = gridDim.x * 256;
    const f32x4* ep4 = (const f32x4*)e_p;
    const f32x4* xb4 = (const f32x4*)x_block;
#pragma unroll 1
    for (int f = blockIdx.x * 256 + threadIdx.x; f < TOT; f += stride) {
        f32x4 v;
        if (f < XB4) {
            const int g = (f >= EK4) ? f - EK4 : f;
            const int b = g / (4 * DIM / 4);
            const int k = bestk[b];
            const int off = (f >= EK4) ? 4 * (DIM / 4) : 0;
            v = ep4[(size_t)k * (LL * DIM / 4) + off + (g - b * 768)];
        } else {
            v = __builtin_nontemporal_load(&xb4[f - XB4]);
        }
        __builtin_nontemporal_store(v, &o[f]);
    }
}

// ---------- launch ----------
extern "C" void kernel_launch(void* const* d_in, const int* in_sizes, int n_in,
                              void* d_out, int out_size, void* d_ws, size_t ws_size,
                              hipStream_t stream) {
    const float* x_querry = (const float*)d_in[0];
    const float* x_block  = (const float*)d_in[1];
    const float* e_k      = (const float*)d_in[2];
    const float* e_p      = (const float*)d_in[3];

    // scratch carved from d_out (226.5 MB), fully consumed before gather overwrites it
    char* base = (char*)d_out;
    f16*   Xh   = (f16*)(base);                   // 12,582,912 B
    f16*   Eh   = (f16*)(base + 12582912);        //  6,291,456 B
    float* invn = (float*)(base + 18874368);      //     16,384 B
    float* marg = (float*)(base + 18890752);      //     32,768 B
    f16*   scor = (f16*)(base + 18923520);        // 67,108,864 B -> ends 86,032,384
    int*   bestk = (int*)d_ws;                    // 32 KB (survives into gather)

    prep<<<(NQ + NK) / 4, 256, 0, stream>>>(x_querry, e_k, Xh, Eh, marg, invn);
    gemm8p<<<dim3(NQ / 256, NK / 256), 512, 0, stream>>>(Xh, Eh, invn, scor);
    scan_rescore<<<NQ, 256, 0, stream>>>(scor, marg, invn, x_querry, e_k, bestk);
    gather_flat<<<2048, 256, 0, stream>>>(bestk, e_p, x_block, (f32x4*)d_out);
}